// Round 3
// baseline (469.448 us; speedup 1.0000x reference)
//
#include <hip/hip_runtime.h>
#include <math.h>

#define HW_IMG (1u<<20)   // 1024*1024
#define W_ 1024
#define H_ 1024
#define B_ 4
#define C_ 8
#define N_LR 65536        // 256*256

__device__ __forceinline__ int refl1024(int i){
  if(i<0) i=-i;
  if(i>1023) i=2046-i;
  return i;
}

// ---------------- K1: downsample pan + accumulate normal equations ----------
__global__ __launch_bounds__(256) void k_fit(const float* __restrict__ lr_ms,
                                             const float* __restrict__ hr_pan,
                                             double* __restrict__ atab){
  int b = blockIdx.y;
  int tid = blockIdx.x*256 + threadIdx.x;       // 0..16383, each does 4 pixels
  float acc[54];
  #pragma unroll
  for(int i=0;i<54;i++) acc[i]=0.f;
  const float* pan = hr_pan + (size_t)b*HW_IMG;
  const float* lr  = lr_ms + (size_t)b*C_*N_LR;
  for(int k=0;k<4;k++){
    int n = tid*4+k;
    int i = n>>8, j = n&255;
    float s=0.f;
    #pragma unroll
    for(int dy=0;dy<4;dy++){
      const float* pr = pan + (size_t)(i*4+dy)*W_ + j*4;
      s += pr[0]+pr[1]+pr[2]+pr[3];
    }
    float bv = s*(1.f/16.f);
    float a[9];
    a[0]=1.f;
    #pragma unroll
    for(int c=0;c<C_;c++) a[c+1]=lr[(size_t)c*N_LR + n];
    int idx=0;
    #pragma unroll
    for(int p=0;p<9;p++){
      #pragma unroll
      for(int q=p;q<9;q++){ acc[idx] = fmaf(a[p],a[q],acc[idx]); idx++; }
    }
    #pragma unroll
    for(int p=0;p<9;p++) acc[45+p] = fmaf(a[p],bv,acc[45+p]);
  }
  #pragma unroll
  for(int v=0;v<54;v++){
    float x = acc[v];
    for(int off=32;off>0;off>>=1) x += __shfl_down(x, off, 64);
    if((threadIdx.x & 63)==0) atomicAdd(&atab[b*54+v], (double)x);
  }
}

// ---------------- K2: 9x9 solve per batch (f64, partial pivot) -------------
__global__ void k_solve(const double* __restrict__ atab, double* __restrict__ sol){
  int b = threadIdx.x;
  if(b>=B_) return;
  double A[9][10];
  const double* src = atab + b*54;
  int idx=0;
  for(int p=0;p<9;p++)
    for(int q=p;q<9;q++){ A[p][q]=src[idx]; A[q][p]=src[idx]; idx++; }
  for(int p=0;p<9;p++) A[p][9]=src[45+p];
  for(int col=0; col<9; col++){
    int piv=col; double mx=fabs(A[col][col]);
    for(int r=col+1;r<9;r++){ double v=fabs(A[r][col]); if(v>mx){mx=v;piv=r;} }
    if(piv!=col){
      for(int c2=col;c2<10;c2++){ double t=A[col][c2]; A[col][c2]=A[piv][c2]; A[piv][c2]=t; }
    }
    double inv = 1.0/A[col][col];
    for(int r=col+1;r<9;r++){
      double f = A[r][col]*inv;
      for(int c2=col;c2<10;c2++) A[r][c2] -= f*A[col][c2];
    }
  }
  double x[9];
  for(int r=8;r>=0;r--){
    double s=A[r][9];
    for(int c2=r+1;c2<9;c2++) s -= A[r][c2]*x[c2];
    x[r]=s/A[r][r];
  }
  for(int i=0;i<9;i++) sol[b*9+i]=x[i];
}

// ---------------- K3: synthesize M_, G_, D = sum_c |fuse-hr| ---------------
// All 16 float4 loads batched into registers BEFORE compute: ~16 loads in
// flight per thread (was ~2 at 44 VGPRs).
__global__ __launch_bounds__(256,4) void k_synth(const float* __restrict__ hr_ms,
                                                 const float* __restrict__ fuse_ms,
                                                 const double* __restrict__ sol,
                                                 float* __restrict__ M,
                                                 float* __restrict__ G,
                                                 float* __restrict__ D){
  size_t t = (size_t)blockIdx.x*256 + threadIdx.x;   // < 2^20, 4 px each
  int b = (int)(t >> 18);
  size_t pix = (t & (size_t)((1<<18)-1))*4;
  size_t base = (((size_t)b*C_)<<20) + pix;
  float4 hv[8], fv[8];
  #pragma unroll
  for(int c=0;c<C_;c++) hv[c] = *(const float4*)(hr_ms + base + ((size_t)c<<20));
  #pragma unroll
  for(int c=0;c<C_;c++) fv[c] = *(const float4*)(fuse_ms + base + ((size_t)c<<20));
  const double* s = sol + b*9;
  float bias = (float)s[0];
  float4 m = {bias,bias,bias,bias};
  float4 g = m;
  float4 d = {0.f,0.f,0.f,0.f};
  #pragma unroll
  for(int c=0;c<C_;c++){
    float w = (float)s[c+1];
    m.x=fmaf(w,hv[c].x,m.x); m.y=fmaf(w,hv[c].y,m.y); m.z=fmaf(w,hv[c].z,m.z); m.w=fmaf(w,hv[c].w,m.w);
    g.x=fmaf(w,fv[c].x,g.x); g.y=fmaf(w,fv[c].y,g.y); g.z=fmaf(w,fv[c].z,g.z); g.w=fmaf(w,fv[c].w,g.w);
    d.x+=fabsf(fv[c].x-hv[c].x); d.y+=fabsf(fv[c].y-hv[c].y);
    d.z+=fabsf(fv[c].z-hv[c].z); d.w+=fabsf(fv[c].w-hv[c].w);
  }
  size_t p = ((size_t)b<<20) + pix;
  *(float4*)(M+p)=m; *(float4*)(G+p)=g; *(float4*)(D+p)=d;
}

// ---------------- K4: vertical box blur, 4 cols/thread (float4 taps) -------
#define ACC4(S, V, op) { S.x op V.x; S.y op V.y; S.z op V.z; S.w op V.w; }
__global__ __launch_bounds__(256) void k_vblur(const float* __restrict__ M,
                                               const float* __restrict__ P,
                                               const float* __restrict__ G,
                                               float* __restrict__ VB){
  int x4 = threadIdx.x*4;                 // 0..1020, full 1024 width per block
  int b  = blockIdx.x;
  int y0 = blockIdx.y * 8;                // 128 segments of 8 rows
  const float* Mp = M + (size_t)b*HW_IMG;
  const float* Pp = P + (size_t)b*HW_IMG;
  const float* Gp = G + (size_t)b*HW_IMG;
  float4 S0={0,0,0,0},S1=S0,S2=S0,S3=S0,S4=S0,S5=S0,S6=S0;
  #define TAPV(yy, op) { int r = refl1024(yy); size_t off=(size_t)r*W_+x4; \
    float4 mv=*(const float4*)(Mp+off); \
    float4 pv=*(const float4*)(Pp+off); \
    float4 gv=*(const float4*)(Gp+off); \
    ACC4(S0,mv,op) ACC4(S1,pv,op) \
    { float4 tq={mv.x*pv.x,mv.y*pv.y,mv.z*pv.z,mv.w*pv.w}; ACC4(S2,tq,op) } \
    { float4 tq={mv.x*mv.x,mv.y*mv.y,mv.z*mv.z,mv.w*mv.w}; ACC4(S3,tq,op) } \
    { float4 tq={pv.x*pv.x,pv.y*pv.y,pv.z*pv.z,pv.w*pv.w}; ACC4(S4,tq,op) } \
    ACC4(S5,gv,op) \
    { float4 tq={gv.x*gv.x,gv.y*gv.y,gv.z*gv.z,gv.w*gv.w}; ACC4(S6,tq,op) } }
  #pragma unroll
  for(int k=-15;k<=15;k++) TAPV(y0+k, +=);
  const float inv = 1.f/31.f;
  size_t base = (size_t)b*HW_IMG + (size_t)y0*W_ + x4;
  const size_t CH = (size_t)B_*HW_IMG;
  #pragma unroll
  for(int i=0;i<8;i++){
    size_t o = base + (size_t)i*W_;
    #define ST4(ptr, S) { float4 tv={S.x*inv,S.y*inv,S.z*inv,S.w*inv}; *(float4*)(ptr)=tv; }
    ST4(VB+o,      S0) ST4(VB+CH+o,   S1) ST4(VB+2*CH+o, S2)
    ST4(VB+3*CH+o, S3) ST4(VB+4*CH+o, S4) ST4(VB+5*CH+o, S5)
    ST4(VB+6*CH+o, S6)
    #undef ST4
    if(i<7){
      int y = y0+i;
      TAPV(y+16, +=);
      TAPV(y-15, -=);
    }
  }
  #undef TAPV
}

// ---------------- K5: horizontal blur + loss terms -------------------------
#define LIDX(i) ((i)+((i)>>5))
__global__ __launch_bounds__(128) void k_hfinal(const float* __restrict__ VB,
                                                const float* __restrict__ P,
                                                const float* __restrict__ G,
                                                const float* __restrict__ D,
                                                double* __restrict__ partial){
  __shared__ float lds[7*1056];
  __shared__ float red[4];
  int row = blockIdx.x;           // 0..4095
  int b = row>>10, y = row&1023;
  int t = threadIdx.x;            // 0..127
  size_t rowoff = (size_t)b*HW_IMG + (size_t)y*W_;
  const size_t CH = (size_t)B_*HW_IMG;
  for(int ch=0; ch<7; ch++){
    const float* src = VB + (size_t)ch*CH + rowoff;
    float* dst = lds + ch*1056;
    for(int i=t*4; i<1024; i+=512){
      float4 v = *(const float4*)(src+i);
      dst[LIDX(i)]   = v.x;
      dst[LIDX(i+1)] = v.y;
      dst[LIDX(i+2)] = v.z;
      dst[LIDX(i+3)] = v.w;
    }
  }
  int x0 = t*8;
  float pv[8], gv[8], dv[8];
  {
    const float* Pr = P + rowoff + x0;
    const float* Gr = G + rowoff + x0;
    const float* Dr = D + rowoff + x0;
    #pragma unroll
    for(int i=0;i<2;i++){
      float4 a = *(const float4*)(Pr + i*4);
      pv[i*4]=a.x; pv[i*4+1]=a.y; pv[i*4+2]=a.z; pv[i*4+3]=a.w;
      float4 c = *(const float4*)(Gr + i*4);
      gv[i*4]=c.x; gv[i*4+1]=c.y; gv[i*4+2]=c.z; gv[i*4+3]=c.w;
      float4 e = *(const float4*)(Dr + i*4);
      dv[i*4]=e.x; dv[i*4+1]=e.y; dv[i*4+2]=e.z; dv[i*4+3]=e.w;
    }
  }
  __syncthreads();
  float S[7];
  #pragma unroll
  for(int ch=0;ch<7;ch++) S[ch]=0.f;
  #define TAPH(xx, op) { int r=refl1024(xx); int li=LIDX(r); \
    S[0] op lds[li];        S[1] op lds[1056+li];   S[2] op lds[2*1056+li]; \
    S[3] op lds[3*1056+li]; S[4] op lds[4*1056+li]; S[5] op lds[5*1056+li]; \
    S[6] op lds[6*1056+li]; }
  for(int k=x0-15;k<=x0+15;k++) TAPH(k, +=);
  const float inv = 1.f/31.f;
  float lc=0.f, la=0.f;
  #pragma unroll
  for(int i=0;i<8;i++){
    float mM=S[0]*inv, mP=S[1]*inv, mMP=S[2]*inv, mMM=S[3]*inv,
          mPP=S[4]*inv, mG=S[5]*inv, mGG=S[6]*inv;
    float cov  = mMP - mM*mP;
    float stdM = sqrtf(fabsf(mMM - mM*mM)+1e-10f);
    float stdP = sqrtf(fabsf(mPP - mP*mP)+1e-10f);
    float stdG = sqrtf(fabsf(mGG - mG*mG)+1e-10f);
    float corr = cov/(stdM*stdP);
    float c2 = corr*corr;
    float S4v = c2*c2;                       // S = corr^4 >= 0
    float gradP = (pv[i]-mP)/stdP;
    float gradG = (gv[i]-mG)/stdG;
    lc += dv[i]*S4v;                         // sum_c |fuse-hr| * S
    la += fabsf((gradG-gradP)*(2.f-S4v));
    if(i<7){
      int x = x0+i;
      TAPH(x+16, +=);
      TAPH(x-15, -=);
    }
  }
  #undef TAPH
  for(int off=32;off>0;off>>=1){
    lc += __shfl_down(lc, off, 64);
    la += __shfl_down(la, off, 64);
  }
  int wid = t>>6;                 // 0..1
  if((t&63)==0){ red[wid*2]=lc; red[wid*2+1]=la; }
  __syncthreads();
  if(t==0){
    partial[(size_t)row*2]   = (double)red[0]+(double)red[2];
    partial[(size_t)row*2+1] = (double)red[1]+(double)red[3];
  }
}

// ---------------- K6: reduce partials + final scalar -----------------------
__global__ __launch_bounds__(256) void k_out(const double* __restrict__ partial,
                                             float* __restrict__ out){
  int t = threadIdx.x;
  double lc=0.0, la=0.0;
  for(int i=t;i<4096;i+=256){ lc+=partial[2*i]; la+=partial[2*i+1]; }
  for(int off=32;off>0;off>>=1){
    lc += __shfl_down(lc, off, 64);
    la += __shfl_down(la, off, 64);
  }
  __shared__ double red[8];
  int wid = t>>6;
  if((t&63)==0){ red[wid*2]=lc; red[wid*2+1]=la; }
  __syncthreads();
  if(t==0){
    double c = red[0]+red[2]+red[4]+red[6];
    double a = red[1]+red[3]+red[5]+red[7];
    out[0] = (float)(c*(1.0/33554432.0) + a*(1.0/4194304.0));
  }
}

extern "C" void kernel_launch(void* const* d_in, const int* in_sizes, int n_in,
                              void* d_out, int out_size, void* d_ws, size_t ws_size,
                              hipStream_t stream){
  const float* lr_ms   = (const float*)d_in[0];
  const float* hr_pan  = (const float*)d_in[1];
  const float* hr_ms   = (const float*)d_in[2];
  const float* fuse_ms = (const float*)d_in[3];
  float* out = (float*)d_out;

  char* ws = (char*)d_ws;
  double* atab    = (double*)ws;              // 4*54 doubles
  double* sol     = (double*)(ws + 4096);     // 36 doubles
  double* partial = (double*)(ws + 8192);     // 4096*2 doubles = 64 KB
  float* M  = (float*)(ws + 131072);
  float* G  = M + (size_t)B_*HW_IMG;
  float* Dd = G + (size_t)B_*HW_IMG;
  float* VB = Dd + (size_t)B_*HW_IMG;         // 7 channels of B*H*W

  hipMemsetAsync(d_ws, 0, 4096, stream);      // zero atab
  k_fit  <<<dim3(64,4),   256, 0, stream>>>(lr_ms, hr_pan, atab);
  k_solve<<<1,            64,  0, stream>>>(atab, sol);
  k_synth<<<4096,         256, 0, stream>>>(hr_ms, fuse_ms, sol, M, G, Dd);
  k_vblur<<<dim3(4,128),  256, 0, stream>>>(M, hr_pan, G, VB);
  k_hfinal<<<4096,        128, 0, stream>>>(VB, hr_pan, G, Dd, partial);
  k_out  <<<1, 256, 0, stream>>>(partial, out);
}

// Round 4
// 432.690 us; speedup vs baseline: 1.0850x; 1.0850x over previous
//
#include <hip/hip_runtime.h>
#include <math.h>

#define HW_IMG (1u<<20)   // 1024*1024
#define W_ 1024
#define H_ 1024
#define B_ 4
#define C_ 8
#define N_LR 65536        // 256*256

__device__ __forceinline__ int refl1024(int i){
  if(i<0) i=-i;
  if(i>1023) i=2046-i;
  return i;
}

// ---------------- K1: downsample pan + accumulate normal equations ----------
__global__ __launch_bounds__(256) void k_fit(const float* __restrict__ lr_ms,
                                             const float* __restrict__ hr_pan,
                                             double* __restrict__ atab){
  int b = blockIdx.y;
  int tid = blockIdx.x*256 + threadIdx.x;       // 0..16383, each does 4 pixels
  float acc[54];
  #pragma unroll
  for(int i=0;i<54;i++) acc[i]=0.f;
  const float* pan = hr_pan + (size_t)b*HW_IMG;
  const float* lr  = lr_ms + (size_t)b*C_*N_LR;
  for(int k=0;k<4;k++){
    int n = tid*4+k;
    int i = n>>8, j = n&255;
    float s=0.f;
    #pragma unroll
    for(int dy=0;dy<4;dy++){
      const float* pr = pan + (size_t)(i*4+dy)*W_ + j*4;
      s += pr[0]+pr[1]+pr[2]+pr[3];
    }
    float bv = s*(1.f/16.f);
    float a[9];
    a[0]=1.f;
    #pragma unroll
    for(int c=0;c<C_;c++) a[c+1]=lr[(size_t)c*N_LR + n];
    int idx=0;
    #pragma unroll
    for(int p=0;p<9;p++){
      #pragma unroll
      for(int q=p;q<9;q++){ acc[idx] = fmaf(a[p],a[q],acc[idx]); idx++; }
    }
    #pragma unroll
    for(int p=0;p<9;p++) acc[45+p] = fmaf(a[p],bv,acc[45+p]);
  }
  #pragma unroll
  for(int v=0;v<54;v++){
    float x = acc[v];
    for(int off=32;off>0;off>>=1) x += __shfl_down(x, off, 64);
    if((threadIdx.x & 63)==0) atomicAdd(&atab[b*54+v], (double)x);
  }
}

// ---------------- K2: 9x9 solve per batch (f64, partial pivot) -------------
__global__ void k_solve(const double* __restrict__ atab, double* __restrict__ sol){
  int b = threadIdx.x;
  if(b>=B_) return;
  double A[9][10];
  const double* src = atab + b*54;
  int idx=0;
  for(int p=0;p<9;p++)
    for(int q=p;q<9;q++){ A[p][q]=src[idx]; A[q][p]=src[idx]; idx++; }
  for(int p=0;p<9;p++) A[p][9]=src[45+p];
  for(int col=0; col<9; col++){
    int piv=col; double mx=fabs(A[col][col]);
    for(int r=col+1;r<9;r++){ double v=fabs(A[r][col]); if(v>mx){mx=v;piv=r;} }
    if(piv!=col){
      for(int c2=col;c2<10;c2++){ double t=A[col][c2]; A[col][c2]=A[piv][c2]; A[piv][c2]=t; }
    }
    double inv = 1.0/A[col][col];
    for(int r=col+1;r<9;r++){
      double f = A[r][col]*inv;
      for(int c2=col;c2<10;c2++) A[r][c2] -= f*A[col][c2];
    }
  }
  double x[9];
  for(int r=8;r>=0;r--){
    double s=A[r][9];
    for(int c2=r+1;c2<9;c2++) s -= A[r][c2]*x[c2];
    x[r]=s/A[r][r];
  }
  for(int i=0;i<9;i++) sol[b*9+i]=x[i];
}

// ---------------- K3: synthesize M_, G_, D (grid-stride, steady-state) -----
// 1024 blocks x 256 thr, 4 iterations/thread (one batch image per iteration,
// b == iteration index since 1024*256 == 2^18 quads per image).
__global__ __launch_bounds__(256) void k_synth(const float* __restrict__ hr_ms,
                                               const float* __restrict__ fuse_ms,
                                               const double* __restrict__ sol,
                                               float* __restrict__ M,
                                               float* __restrict__ G,
                                               float* __restrict__ D){
  size_t pix = ((size_t)blockIdx.x*256 + threadIdx.x)*4;   // 0..2^20-4
  #pragma unroll
  for(int b=0;b<B_;b++){
    const double* s = sol + b*9;
    float bias = (float)s[0];
    float4 m = {bias,bias,bias,bias};
    float4 g = m;
    float4 d = {0.f,0.f,0.f,0.f};
    #pragma unroll
    for(int c=0;c<C_;c++){
      float w = (float)s[c+1];
      size_t off = (((size_t)(b*C_+c))<<20) + pix;
      float4 hv = *(const float4*)(hr_ms+off);
      float4 fv = *(const float4*)(fuse_ms+off);
      m.x=fmaf(w,hv.x,m.x); m.y=fmaf(w,hv.y,m.y); m.z=fmaf(w,hv.z,m.z); m.w=fmaf(w,hv.w,m.w);
      g.x=fmaf(w,fv.x,g.x); g.y=fmaf(w,fv.y,g.y); g.z=fmaf(w,fv.z,g.z); g.w=fmaf(w,fv.w,g.w);
      d.x+=fabsf(fv.x-hv.x); d.y+=fabsf(fv.y-hv.y);
      d.z+=fabsf(fv.z-hv.z); d.w+=fabsf(fv.w-hv.w);
    }
    size_t p = ((size_t)b<<20) + pix;
    *(float4*)(M+p)=m; *(float4*)(G+p)=g; *(float4*)(D+p)=d;
  }
}

// ---------------- K4: FUSED vertical+horizontal blur + loss ----------------
// 8-row strips. Vertical running sums in registers (4 cols/thread, float4),
// one row-pair of vertical sums staged in swizzled LDS, then the horizontal
// sliding window + loss math (identical arithmetic to the R2 k_hfinal).
#define LIDX(i) ((i)+((i)>>5))
#define ACC4(S, V, op) { S.x op V.x; S.y op V.y; S.z op V.z; S.w op V.w; }
__global__ __launch_bounds__(256) void k_vh(const float* __restrict__ M,
                                            const float* __restrict__ P,
                                            const float* __restrict__ G,
                                            const float* __restrict__ D,
                                            double* __restrict__ partial){
  __shared__ float vs[2][7][1056];  // [row parity][channel][swizzled 1024]
  __shared__ float red[8];
  int t  = threadIdx.x;            // 0..255
  int y0 = blockIdx.x*8;           // strip base row (128 strips)
  int b  = blockIdx.y;
  const float* Mp = M + (size_t)b*HW_IMG;
  const float* Pp = P + (size_t)b*HW_IMG;
  const float* Gp = G + (size_t)b*HW_IMG;
  int x4 = t*4;                    // vertical ownership: 4 columns
  const float inv = 1.f/31.f;

  float4 S0={0,0,0,0},S1=S0,S2=S0,S3=S0,S4=S0,S5=S0,S6=S0;
  #define TAPV(yy, op) { int r_ = refl1024(yy); size_t off=(size_t)r_*W_+x4; \
    float4 mv=*(const float4*)(Mp+off); \
    float4 pv_=*(const float4*)(Pp+off); \
    float4 gv_=*(const float4*)(Gp+off); \
    ACC4(S0,mv,op) ACC4(S1,pv_,op) \
    { float4 tq={mv.x*pv_.x,mv.y*pv_.y,mv.z*pv_.z,mv.w*pv_.w}; ACC4(S2,tq,op) } \
    { float4 tq={mv.x*mv.x,mv.y*mv.y,mv.z*mv.z,mv.w*mv.w}; ACC4(S3,tq,op) } \
    { float4 tq={pv_.x*pv_.x,pv_.y*pv_.y,pv_.z*pv_.z,pv_.w*pv_.w}; ACC4(S4,tq,op) } \
    ACC4(S5,gv_,op) \
    { float4 tq={gv_.x*gv_.x,gv_.y*gv_.y,gv_.z*gv_.z,gv_.w*gv_.w}; ACC4(S6,tq,op) } }

  for(int k=y0-15;k<y0+15;k++) TAPV(k, +=);   // 30 taps: rows y0-15..y0+14

  float lc=0.f, la=0.f;
  int xh = (t&127)*8;              // horizontal ownership: 8 px
  int rsel = t>>7;                 // which staged row this thread finalizes

  for(int stage=0; stage<4; stage++){
    #pragma unroll
    for(int rr=0; rr<2; rr++){
      int r = y0 + stage*2 + rr;
      TAPV(r+15, +=);
      // stage vertical means (x inv) into LDS, swizzled scalar stores
      #define STV(ch, S) { float* dst = &vs[rr][ch][0]; \
        dst[LIDX(x4)]  =S.x*inv; dst[LIDX(x4+1)]=S.y*inv; \
        dst[LIDX(x4+2)]=S.z*inv; dst[LIDX(x4+3)]=S.w*inv; }
      STV(0,S0) STV(1,S1) STV(2,S2) STV(3,S3) STV(4,S4) STV(5,S5) STV(6,S6)
      #undef STV
      TAPV(r-15, -=);
    }
    __syncthreads();
    // ---- horizontal phase: 128 threads per staged row, 8 px each ----
    int rh = y0 + stage*2 + rsel;
    size_t rowoff = (size_t)b*HW_IMG + (size_t)rh*W_;
    float pv[8], gv[8], dv[8];
    {
      const float* Pr = Pp + (size_t)rh*W_ + xh;
      const float* Gr = Gp + (size_t)rh*W_ + xh;
      const float* Dr = D + rowoff + xh;
      #pragma unroll
      for(int i=0;i<2;i++){
        float4 a = *(const float4*)(Pr + i*4);
        pv[i*4]=a.x; pv[i*4+1]=a.y; pv[i*4+2]=a.z; pv[i*4+3]=a.w;
        float4 c = *(const float4*)(Gr + i*4);
        gv[i*4]=c.x; gv[i*4+1]=c.y; gv[i*4+2]=c.z; gv[i*4+3]=c.w;
        float4 e = *(const float4*)(Dr + i*4);
        dv[i*4]=e.x; dv[i*4+1]=e.y; dv[i*4+2]=e.z; dv[i*4+3]=e.w;
      }
    }
    float Wc[7];
    #pragma unroll
    for(int ch=0;ch<7;ch++) Wc[ch]=0.f;
    #define TAPH(xx, op) { int r_=refl1024(xx); int li=LIDX(r_); \
      Wc[0] op vs[rsel][0][li]; Wc[1] op vs[rsel][1][li]; Wc[2] op vs[rsel][2][li]; \
      Wc[3] op vs[rsel][3][li]; Wc[4] op vs[rsel][4][li]; Wc[5] op vs[rsel][5][li]; \
      Wc[6] op vs[rsel][6][li]; }
    for(int k=xh-15;k<=xh+15;k++) TAPH(k, +=);
    #pragma unroll
    for(int i=0;i<8;i++){
      float mM=Wc[0]*inv, mP=Wc[1]*inv, mMP=Wc[2]*inv, mMM=Wc[3]*inv,
            mPP=Wc[4]*inv, mG=Wc[5]*inv, mGG=Wc[6]*inv;
      float cov  = mMP - mM*mP;
      float stdM = sqrtf(fabsf(mMM - mM*mM)+1e-10f);
      float stdP = sqrtf(fabsf(mPP - mP*mP)+1e-10f);
      float stdG = sqrtf(fabsf(mGG - mG*mG)+1e-10f);
      float corr = cov/(stdM*stdP);
      float c2 = corr*corr;
      float S4v = c2*c2;                     // S = corr^4 >= 0
      float gradP = (pv[i]-mP)/stdP;
      float gradG = (gv[i]-mG)/stdG;
      lc += dv[i]*S4v;                       // sum_c |fuse-hr| * S
      la += fabsf((gradG-gradP)*(2.f-S4v));
      if(i<7){
        int x = xh+i;
        TAPH(x+16, +=);
        TAPH(x-15, -=);
      }
    }
    #undef TAPH
    __syncthreads();
  }
  #undef TAPV

  for(int off=32;off>0;off>>=1){
    lc += __shfl_down(lc, off, 64);
    la += __shfl_down(la, off, 64);
  }
  int wid = t>>6;                  // 0..3
  if((t&63)==0){ red[wid*2]=lc; red[wid*2+1]=la; }
  __syncthreads();
  if(t==0){
    int blk = blockIdx.y*gridDim.x + blockIdx.x;
    partial[(size_t)blk*2]   = (double)red[0]+(double)red[2]+(double)red[4]+(double)red[6];
    partial[(size_t)blk*2+1] = (double)red[1]+(double)red[3]+(double)red[5]+(double)red[7];
  }
}

// ---------------- K6: reduce partials + final scalar -----------------------
__global__ __launch_bounds__(256) void k_out(const double* __restrict__ partial,
                                             float* __restrict__ out){
  int t = threadIdx.x;
  double lc=0.0, la=0.0;
  for(int i=t;i<512;i+=256){ lc+=partial[2*i]; la+=partial[2*i+1]; }
  for(int off=32;off>0;off>>=1){
    lc += __shfl_down(lc, off, 64);
    la += __shfl_down(la, off, 64);
  }
  __shared__ double red[8];
  int wid = t>>6;
  if((t&63)==0){ red[wid*2]=lc; red[wid*2+1]=la; }
  __syncthreads();
  if(t==0){
    double c = red[0]+red[2]+red[4]+red[6];
    double a = red[1]+red[3]+red[5]+red[7];
    out[0] = (float)(c*(1.0/33554432.0) + a*(1.0/4194304.0));
  }
}

extern "C" void kernel_launch(void* const* d_in, const int* in_sizes, int n_in,
                              void* d_out, int out_size, void* d_ws, size_t ws_size,
                              hipStream_t stream){
  const float* lr_ms   = (const float*)d_in[0];
  const float* hr_pan  = (const float*)d_in[1];
  const float* hr_ms   = (const float*)d_in[2];
  const float* fuse_ms = (const float*)d_in[3];
  float* out = (float*)d_out;

  char* ws = (char*)d_ws;
  double* atab    = (double*)ws;              // 4*54 doubles
  double* sol     = (double*)(ws + 4096);     // 36 doubles
  double* partial = (double*)(ws + 8192);     // 512*2 doubles = 8 KB
  float* M  = (float*)(ws + 131072);
  float* G  = M + (size_t)B_*HW_IMG;
  float* Dd = G + (size_t)B_*HW_IMG;

  hipMemsetAsync(d_ws, 0, 4096, stream);      // zero atab
  k_fit  <<<dim3(64,4),   256, 0, stream>>>(lr_ms, hr_pan, atab);
  k_solve<<<1,            64,  0, stream>>>(atab, sol);
  k_synth<<<1024,         256, 0, stream>>>(hr_ms, fuse_ms, sol, M, G, Dd);
  k_vh   <<<dim3(128,4),  256, 0, stream>>>(M, hr_pan, G, Dd, partial);
  k_out  <<<1, 256, 0, stream>>>(partial, out);
}